// Round 2
// baseline (178.261 us; speedup 1.0000x reference)
//
#include <hip/hip_runtime.h>

// ConfusionAwareLoss: mean over B rows of
//   (max + log(sum exp(x - max)) - x[target]) * penalty[target, argmax]
// B=131072, C=1000 fp32. Memory-bound: one 524 MB streaming read.
// Single fused kernel: last-block pattern for the final reduce (fixed-order
// -> deterministic across graph replays). Streaming loads are nontemporal.

#define NCLASS   1000
#define NC4      250      // float4 per row (1000/4)
#define BLK      256      // 4 waves per block
#define WPB      4
#define NBLOCKS  2048     // 8192 waves, 16 rows/wave

typedef float f32x4 __attribute__((ext_vector_type(4)));

__global__ __launch_bounds__(BLK) void cal_fused(
    const float* __restrict__ outputs,
    const int*   __restrict__ targets,
    const float* __restrict__ penalty,
    float*       __restrict__ partials,   // [gridDim.x]
    unsigned*    __restrict__ counter,    // zeroed via hipMemsetAsync per call
    float*       __restrict__ out,
    int B, float invB)
{
    const int lane  = threadIdx.x & 63;
    const int widx  = threadIdx.x >> 6;
    const int gwave = blockIdx.x * WPB + widx;
    const int nwave = gridDim.x * WPB;

    float acc = 0.0f;

    for (int row = gwave; row < B; row += nwave) {
        const f32x4* rp = reinterpret_cast<const f32x4*>(outputs + (size_t)row * NCLASS);
        const float NEG = -__builtin_inff();

        // whole row in registers: 4 x float4 per lane, coalesced 16B/lane,
        // nontemporal (streamed once; keep L2 for the penalty table)
        f32x4 v0 = __builtin_nontemporal_load(rp + lane);
        f32x4 v1 = __builtin_nontemporal_load(rp + lane + 64);
        f32x4 v2 = __builtin_nontemporal_load(rp + lane + 128);
        f32x4 v3;
        const int c3 = lane + 192;
        if (c3 < NC4) v3 = __builtin_nontemporal_load(rp + c3);
        else { v3.x = NEG; v3.y = NEG; v3.z = NEG; v3.w = NEG; }

        // per-lane max + argmax (first occurrence: strictly-greater over
        // ascending column order within the lane)
        float mval = v0.x; int midx = 4 * lane;
        #define UPD(val, col) do { if ((val) > mval) { mval = (val); midx = (col); } } while (0)
        UPD(v0.y, 4*lane + 1); UPD(v0.z, 4*lane + 2); UPD(v0.w, 4*lane + 3);
        { int b = 4*(lane +  64); UPD(v1.x, b); UPD(v1.y, b+1); UPD(v1.z, b+2); UPD(v1.w, b+3); }
        { int b = 4*(lane + 128); UPD(v2.x, b); UPD(v2.y, b+1); UPD(v2.z, b+2); UPD(v2.w, b+3); }
        { int b = 4*(lane + 192); UPD(v3.x, b); UPD(v3.y, b+1); UPD(v3.z, b+2); UPD(v3.w, b+3); }
        #undef UPD

        // 64-lane butterfly (max, argmax); smaller index wins ties
        #pragma unroll
        for (int off = 32; off > 0; off >>= 1) {
            float ov = __shfl_xor(mval, off, 64);
            int   oi = __shfl_xor(midx, off, 64);
            if (ov > mval || (ov == mval && oi < midx)) { mval = ov; midx = oi; }
        }

        // sum exp(x - max); pad lanes contribute exp(-inf) = 0
        float s;
        s  = __expf(v0.x - mval) + __expf(v0.y - mval) + __expf(v0.z - mval) + __expf(v0.w - mval);
        s += __expf(v1.x - mval) + __expf(v1.y - mval) + __expf(v1.z - mval) + __expf(v1.w - mval);
        s += __expf(v2.x - mval) + __expf(v2.y - mval) + __expf(v2.z - mval) + __expf(v2.w - mval);
        s += __expf(v3.x - mval) + __expf(v3.y - mval) + __expf(v3.z - mval) + __expf(v3.w - mval);
        #pragma unroll
        for (int off = 32; off > 0; off >>= 1) s += __shfl_xor(s, off, 64);

        // target logit: uniform (jt, et) select chain — no runtime array index
        const int t   = targets[row];
        const int c4t = t >> 2;
        const int lt  = c4t & 63;
        const int jt  = c4t >> 6;
        const int et  = t & 3;
        f32x4 vv = (jt == 0) ? v0 : (jt == 1) ? v1 : (jt == 2) ? v2 : v3;
        float  xe = (et == 0) ? vv.x : (et == 1) ? vv.y : (et == 2) ? vv.z : vv.w;
        float tval = __shfl(xe, lt, 64);

        if (lane == 0) {
            float pen = penalty[(size_t)t * NCLASS + midx];
            acc += (mval + __logf(s) - tval) * pen;
        }
    }

    // block partial
    __shared__ float wsum[WPB];
    __shared__ int is_last;
    if (lane == 0) wsum[widx] = acc;
    __syncthreads();
    if (threadIdx.x == 0) {
        partials[blockIdx.x] = wsum[0] + wsum[1] + wsum[2] + wsum[3];
        __threadfence();                                  // release partial (device scope)
        unsigned prev = atomicAdd(counter, 1u);           // device-scope by default
        is_last = (prev == (unsigned)gridDim.x - 1u) ? 1 : 0;
    }
    __syncthreads();

    // last block: fixed-order reduce of all partials -> deterministic
    if (is_last) {
        __threadfence();                                  // acquire: see all partials
        float s = 0.0f;
        for (int i = threadIdx.x; i < gridDim.x; i += BLK)
            s += partials[i];
        #pragma unroll
        for (int off = 32; off > 0; off >>= 1) s += __shfl_xor(s, off, 64);
        __shared__ float fsum[WPB];
        if (lane == 0) fsum[widx] = s;
        __syncthreads();
        if (threadIdx.x == 0)
            out[0] = (fsum[0] + fsum[1] + fsum[2] + fsum[3]) * invB;
    }
}

extern "C" void kernel_launch(void* const* d_in, const int* in_sizes, int n_in,
                              void* d_out, int out_size, void* d_ws, size_t ws_size,
                              hipStream_t stream)
{
    const float* outputs = (const float*)d_in[0];
    const int*   targets = (const int*)d_in[1];
    const float* penalty = (const float*)d_in[2];
    float* out = (float*)d_out;
    const int B = in_sizes[1];

    // ws layout: [0,4) counter | [256, 256 + grid*4) partials
    unsigned* counter  = (unsigned*)d_ws;
    float*    partials = (float*)((char*)d_ws + 256);
    int grid = NBLOCKS;
    if (ws_size < 256 + (size_t)grid * sizeof(float))
        grid = (int)((ws_size - 256) / sizeof(float));   // defensive; expect ws big enough

    hipMemsetAsync(counter, 0, sizeof(unsigned), stream);
    cal_fused<<<grid, BLK, 0, stream>>>(outputs, targets, penalty, partials,
                                        counter, out, B, 1.0f / (float)B);
}

// Round 3
// 109.988 us; speedup vs baseline: 1.6207x; 1.6207x over previous
//
#include <hip/hip_runtime.h>

// ConfusionAwareLoss: mean over B rows of
//   (max + log(sum exp(x - max)) - x[target]) * penalty[target, argmax]
// B=131072, C=1000 fp32. Memory-bound: one 524 MB streaming read.
//
// R3: two-kernel structure (R2's fused last-block + threadfence + memset
// regressed 97->178us; reverted). Single change vs R1:
//   - contiguous rows per wave + 1-row software prefetch (loads for row i+1
//     in flight during row i's compute) to lift read BW 5.7 -> ~6.4 TB/s.

#define NCLASS   1000
#define NC4      250      // float4 per row (1000/4)
#define BLK      256      // 4 waves per block
#define WPB      4
#define RPW      16       // rows per wave, contiguous

typedef float f32x4 __attribute__((ext_vector_type(4)));

__device__ __forceinline__ void load_row(const float* __restrict__ outputs,
                                         int row, int lane,
                                         f32x4& v0, f32x4& v1, f32x4& v2, f32x4& v3)
{
    const f32x4* rp = reinterpret_cast<const f32x4*>(outputs + (size_t)row * NCLASS);
    const float NEG = -__builtin_inff();
    v0 = rp[lane];
    v1 = rp[lane + 64];
    v2 = rp[lane + 128];
    if (lane + 192 < NC4) v3 = rp[lane + 192];
    else { v3.x = NEG; v3.y = NEG; v3.z = NEG; v3.w = NEG; }
}

// returns the weighted loss term on lane 0 (0 on other lanes)
__device__ __forceinline__ float row_term(f32x4 v0, f32x4 v1, f32x4 v2, f32x4 v3,
                                          int t, int lane,
                                          const float* __restrict__ penalty)
{
    // per-lane max + argmax (first occurrence: strictly-greater over
    // ascending column order within the lane)
    float mval = v0.x; int midx = 4 * lane;
    #define UPD(val, col) do { if ((val) > mval) { mval = (val); midx = (col); } } while (0)
    UPD(v0.y, 4*lane + 1); UPD(v0.z, 4*lane + 2); UPD(v0.w, 4*lane + 3);
    { int b = 4*(lane +  64); UPD(v1.x, b); UPD(v1.y, b+1); UPD(v1.z, b+2); UPD(v1.w, b+3); }
    { int b = 4*(lane + 128); UPD(v2.x, b); UPD(v2.y, b+1); UPD(v2.z, b+2); UPD(v2.w, b+3); }
    { int b = 4*(lane + 192); UPD(v3.x, b); UPD(v3.y, b+1); UPD(v3.z, b+2); UPD(v3.w, b+3); }
    #undef UPD

    // 64-lane butterfly (max, argmax); smaller index wins ties
    #pragma unroll
    for (int off = 32; off > 0; off >>= 1) {
        float ov = __shfl_xor(mval, off, 64);
        int   oi = __shfl_xor(midx, off, 64);
        if (ov > mval || (ov == mval && oi < midx)) { mval = ov; midx = oi; }
    }

    // sum exp(x - max); pad lanes contribute exp(-inf) = 0
    float s;
    s  = __expf(v0.x - mval) + __expf(v0.y - mval) + __expf(v0.z - mval) + __expf(v0.w - mval);
    s += __expf(v1.x - mval) + __expf(v1.y - mval) + __expf(v1.z - mval) + __expf(v1.w - mval);
    s += __expf(v2.x - mval) + __expf(v2.y - mval) + __expf(v2.z - mval) + __expf(v2.w - mval);
    s += __expf(v3.x - mval) + __expf(v3.y - mval) + __expf(v3.z - mval) + __expf(v3.w - mval);
    #pragma unroll
    for (int off = 32; off > 0; off >>= 1) s += __shfl_xor(s, off, 64);

    // target logit: uniform (jt, et) select chain — no runtime array index
    const int c4t = t >> 2;
    const int lt  = c4t & 63;
    const int jt  = c4t >> 6;
    const int et  = t & 3;
    f32x4 vv = (jt == 0) ? v0 : (jt == 1) ? v1 : (jt == 2) ? v2 : v3;
    float  xe = (et == 0) ? vv.x : (et == 1) ? vv.y : (et == 2) ? vv.z : vv.w;
    float tval = __shfl(xe, lt, 64);

    float term = 0.0f;
    if (lane == 0) {
        float pen = penalty[(size_t)t * NCLASS + midx];
        term = (mval + __logf(s) - tval) * pen;
    }
    return term;
}

__global__ __launch_bounds__(BLK) void cal_rows(
    const float* __restrict__ outputs,
    const int*   __restrict__ targets,
    const float* __restrict__ penalty,
    float*       __restrict__ partials,
    int B)
{
    const int lane  = threadIdx.x & 63;
    const int widx  = threadIdx.x >> 6;
    const int gwave = blockIdx.x * WPB + widx;

    const int r0   = gwave * RPW;
    const int rend = min(r0 + RPW, B);

    float acc = 0.0f;

    if (r0 < rend) {
        // prime the pipeline: row r0 in flight
        f32x4 a0, a1, a2, a3;
        load_row(outputs, r0, lane, a0, a1, a2, a3);
        int t_cur = targets[r0];

        int row = r0;
        for (; row + 1 < rend; ++row) {
            // issue next row's loads before current row's compute
            f32x4 b0, b1, b2, b3;
            load_row(outputs, row + 1, lane, b0, b1, b2, b3);
            int t_nxt = targets[row + 1];

            acc += row_term(a0, a1, a2, a3, t_cur, lane, penalty);

            a0 = b0; a1 = b1; a2 = b2; a3 = b3; t_cur = t_nxt;
        }
        acc += row_term(a0, a1, a2, a3, t_cur, lane, penalty);
    }

    __shared__ float wsum[WPB];
    if (lane == 0) wsum[widx] = acc;
    __syncthreads();
    if (threadIdx.x == 0)
        partials[blockIdx.x] = wsum[0] + wsum[1] + wsum[2] + wsum[3];
}

__global__ __launch_bounds__(256) void cal_final(
    const float* __restrict__ partials, int n, float* __restrict__ out, float invB)
{
    float s = 0.0f;
    for (int i = threadIdx.x; i < n; i += 256) s += partials[i];
    #pragma unroll
    for (int off = 32; off > 0; off >>= 1) s += __shfl_xor(s, off, 64);
    __shared__ float wsum[4];
    const int widx = threadIdx.x >> 6;
    const int lane = threadIdx.x & 63;
    if (lane == 0) wsum[widx] = s;
    __syncthreads();
    if (threadIdx.x == 0) out[0] = (wsum[0] + wsum[1] + wsum[2] + wsum[3]) * invB;
}

extern "C" void kernel_launch(void* const* d_in, const int* in_sizes, int n_in,
                              void* d_out, int out_size, void* d_ws, size_t ws_size,
                              hipStream_t stream)
{
    const float* outputs = (const float*)d_in[0];
    const int*   targets = (const int*)d_in[1];
    const float* penalty = (const float*)d_in[2];
    float* out = (float*)d_out;
    const int B = in_sizes[1];

    int grid = (B + WPB * RPW - 1) / (WPB * RPW);   // 2048 for B=131072
    float* partials = (float*)d_ws;
    if (ws_size < (size_t)grid * sizeof(float))
        grid = (int)(ws_size / sizeof(float));       // defensive; expect ws >= 8 KB

    cal_rows<<<grid, BLK, 0, stream>>>(outputs, targets, penalty, partials, B);
    cal_final<<<1, 256, 0, stream>>>(partials, grid, out, 1.0f / (float)B);
}

// Round 4
// 102.877 us; speedup vs baseline: 1.7328x; 1.0691x over previous
//
#include <hip/hip_runtime.h>

// ConfusionAwareLoss: mean over B rows of
//   (max + log(sum exp(x - max)) - x[target]) * penalty[target, argmax]
// B=131072, C=1000 fp32. Memory-bound: one 524 MB streaming read.
//
// R4: back to R1's grid-stride two-kernel structure (R3's contiguous+manual
// prefetch dropped the occupancy tier; reverted). Changes vs R1:
//   - target logit extracted right after loads (frees row registers early)
//   - lane-local max/argmax/expsum, then ONE combined (m,idx,s) butterfly
//     (online-softmax merge) -> shorter dependent chain, ~40 live VGPRs
//   - __launch_bounds__(256, 8) pins the 8-waves/SIMD occupancy tier

#define NCLASS   1000
#define NC4      250      // float4 per row (1000/4)
#define BLK      256      // 4 waves per block
#define WPB      4
#define NBLOCKS  2048     // 8192 waves resident = 32/CU at 8/SIMD

typedef float f32x4 __attribute__((ext_vector_type(4)));

__global__ __launch_bounds__(BLK, 8) void cal_rows(
    const float* __restrict__ outputs,
    const int*   __restrict__ targets,
    const float* __restrict__ penalty,
    float*       __restrict__ partials,
    int B)
{
    const int lane  = threadIdx.x & 63;
    const int widx  = threadIdx.x >> 6;
    const int gwave = blockIdx.x * WPB + widx;
    const int nwave = gridDim.x * WPB;

    float acc = 0.0f;

    for (int row = gwave; row < B; row += nwave) {
        const f32x4* rp = reinterpret_cast<const f32x4*>(outputs + (size_t)row * NCLASS);
        const float NEG = -__builtin_inff();

        // whole row in registers: 4 x float4 per lane, coalesced 16B/lane
        f32x4 v0 = rp[lane];
        f32x4 v1 = rp[lane + 64];
        f32x4 v2 = rp[lane + 128];
        f32x4 v3;
        if (lane + 192 < NC4) v3 = rp[lane + 192];
        else { v3.x = NEG; v3.y = NEG; v3.z = NEG; v3.w = NEG; }

        // --- target logit first (row is wave-uniform -> t is scalar) ---
        const int t   = targets[row];
        const int c4t = t >> 2;
        const int lt  = c4t & 63;
        const int jt  = c4t >> 6;
        const int et  = t & 3;
        f32x4 vv = (jt == 0) ? v0 : (jt == 1) ? v1 : (jt == 2) ? v2 : v3;
        float  xe = (et == 0) ? vv.x : (et == 1) ? vv.y : (et == 2) ? vv.z : vv.w;
        const float tval = __shfl(xe, lt, 64);

        // --- lane-local max + argmax (first occurrence within lane) ---
        float mval = v0.x; int midx = 4 * lane;
        #define UPD(val, col) do { if ((val) > mval) { mval = (val); midx = (col); } } while (0)
        UPD(v0.y, 4*lane + 1); UPD(v0.z, 4*lane + 2); UPD(v0.w, 4*lane + 3);
        { int b = 4*(lane +  64); UPD(v1.x, b); UPD(v1.y, b+1); UPD(v1.z, b+2); UPD(v1.w, b+3); }
        { int b = 4*(lane + 128); UPD(v2.x, b); UPD(v2.y, b+1); UPD(v2.z, b+2); UPD(v2.w, b+3); }
        { int b = 4*(lane + 192); UPD(v3.x, b); UPD(v3.y, b+1); UPD(v3.z, b+2); UPD(v3.w, b+3); }
        #undef UPD

        // --- lane-local exp-sum vs lane max; v0..v3 die here ---
        float s;
        s  = __expf(v0.x - mval) + __expf(v0.y - mval) + __expf(v0.z - mval) + __expf(v0.w - mval);
        s += __expf(v1.x - mval) + __expf(v1.y - mval) + __expf(v1.z - mval) + __expf(v1.w - mval);
        s += __expf(v2.x - mval) + __expf(v2.y - mval) + __expf(v2.z - mval) + __expf(v2.w - mval);
        s += __expf(v3.x - mval) + __expf(v3.y - mval) + __expf(v3.z - mval) + __expf(v3.w - mval);

        // --- one combined butterfly: (m, idx, s) online-softmax merge ---
        #pragma unroll
        for (int off = 32; off > 0; off >>= 1) {
            float om = __shfl_xor(mval, off, 64);
            float os = __shfl_xor(s,    off, 64);
            int   oi = __shfl_xor(midx, off, 64);
            float nm = fmaxf(mval, om);
            s = s * __expf(mval - nm) + os * __expf(om - nm);
            if (om > mval || (om == mval && oi < midx)) midx = oi;
            mval = nm;
        }

        if (lane == 0) {
            float pen = penalty[(size_t)t * NCLASS + midx];
            acc += (mval + __logf(s) - tval) * pen;
        }
    }

    __shared__ float wsum[WPB];
    if (lane == 0) wsum[widx] = acc;
    __syncthreads();
    if (threadIdx.x == 0)
        partials[blockIdx.x] = wsum[0] + wsum[1] + wsum[2] + wsum[3];
}

__global__ __launch_bounds__(256) void cal_final(
    const float* __restrict__ partials, int n, float* __restrict__ out, float invB)
{
    float s = 0.0f;
    for (int i = threadIdx.x; i < n; i += 256) s += partials[i];
    #pragma unroll
    for (int off = 32; off > 0; off >>= 1) s += __shfl_xor(s, off, 64);
    __shared__ float wsum[4];
    const int widx = threadIdx.x >> 6;
    const int lane = threadIdx.x & 63;
    if (lane == 0) wsum[widx] = s;
    __syncthreads();
    if (threadIdx.x == 0) out[0] = (wsum[0] + wsum[1] + wsum[2] + wsum[3]) * invB;
}

extern "C" void kernel_launch(void* const* d_in, const int* in_sizes, int n_in,
                              void* d_out, int out_size, void* d_ws, size_t ws_size,
                              hipStream_t stream)
{
    const float* outputs = (const float*)d_in[0];
    const int*   targets = (const int*)d_in[1];
    const float* penalty = (const float*)d_in[2];
    float* out = (float*)d_out;
    const int B = in_sizes[1];

    int grid = NBLOCKS;
    float* partials = (float*)d_ws;
    if (ws_size < (size_t)grid * sizeof(float))
        grid = (int)(ws_size / sizeof(float));   // defensive; expect ws >= 8 KB

    cal_rows<<<grid, BLK, 0, stream>>>(outputs, targets, penalty, partials, B);
    cal_final<<<1, 256, 0, stream>>>(partials, grid, out, 1.0f / (float)B);
}

// Round 5
// 86.983 us; speedup vs baseline: 2.0494x; 1.1827x over previous
//
#include <hip/hip_runtime.h>

// ConfusionAwareLoss: mean over B rows of
//   (max + log(sum exp(x - max)) - x[target]) * penalty[target, argmax]
// B=131072, C=1000 fp32. Memory-bound: one 524 MB streaming read.
//
// R5 = exact R1 structure (97us champion; R2/R3/R4 experiments all reverted)
// with two narrow deltas:
//   - nontemporal loads on the outputs stream (read-once; keep penalty in L2)
//   - 1024-thread finalize kernel (shave the serialized tail)

#define NCLASS   1000
#define NC4      250      // float4 per row (1000/4)
#define BLK      256      // 4 waves per block
#define WPB      4
#define NBLOCKS  2048     // 8192 waves, 16 rows/wave (grid-stride)

typedef float f32x4 __attribute__((ext_vector_type(4)));

__global__ __launch_bounds__(BLK) void cal_rows(
    const float* __restrict__ outputs,
    const int*   __restrict__ targets,
    const float* __restrict__ penalty,
    float*       __restrict__ partials,
    int B)
{
    const int lane  = threadIdx.x & 63;
    const int widx  = threadIdx.x >> 6;
    const int gwave = blockIdx.x * WPB + widx;
    const int nwave = gridDim.x * WPB;

    float acc = 0.0f;

    for (int row = gwave; row < B; row += nwave) {
        const f32x4* rp = reinterpret_cast<const f32x4*>(outputs + (size_t)row * NCLASS);
        const float NEG = -__builtin_inff();

        // whole row in registers: 4 x float4 per lane, coalesced 16B/lane,
        // nontemporal: stream is read-once, keep L2 for the penalty table
        f32x4 v0 = __builtin_nontemporal_load(rp + lane);
        f32x4 v1 = __builtin_nontemporal_load(rp + lane + 64);
        f32x4 v2 = __builtin_nontemporal_load(rp + lane + 128);
        f32x4 v3;
        if (lane + 192 < NC4) v3 = __builtin_nontemporal_load(rp + lane + 192);
        else { v3.x = NEG; v3.y = NEG; v3.z = NEG; v3.w = NEG; }

        // per-lane max + argmax (first occurrence: strictly-greater over
        // ascending column order within the lane)
        float mval = v0.x; int midx = 4 * lane;
        #define UPD(val, col) do { if ((val) > mval) { mval = (val); midx = (col); } } while (0)
        UPD(v0.y, 4*lane + 1); UPD(v0.z, 4*lane + 2); UPD(v0.w, 4*lane + 3);
        { int b = 4*(lane +  64); UPD(v1.x, b); UPD(v1.y, b+1); UPD(v1.z, b+2); UPD(v1.w, b+3); }
        { int b = 4*(lane + 128); UPD(v2.x, b); UPD(v2.y, b+1); UPD(v2.z, b+2); UPD(v2.w, b+3); }
        { int b = 4*(lane + 192); UPD(v3.x, b); UPD(v3.y, b+1); UPD(v3.z, b+2); UPD(v3.w, b+3); }
        #undef UPD

        // 64-lane butterfly (max, argmax); smaller index wins ties
        #pragma unroll
        for (int off = 32; off > 0; off >>= 1) {
            float ov = __shfl_xor(mval, off, 64);
            int   oi = __shfl_xor(midx, off, 64);
            if (ov > mval || (ov == mval && oi < midx)) { mval = ov; midx = oi; }
        }

        // sum exp(x - max); pad lanes contribute exp(-inf) = 0
        float s;
        s  = __expf(v0.x - mval) + __expf(v0.y - mval) + __expf(v0.z - mval) + __expf(v0.w - mval);
        s += __expf(v1.x - mval) + __expf(v1.y - mval) + __expf(v1.z - mval) + __expf(v1.w - mval);
        s += __expf(v2.x - mval) + __expf(v2.y - mval) + __expf(v2.z - mval) + __expf(v2.w - mval);
        s += __expf(v3.x - mval) + __expf(v3.y - mval) + __expf(v3.z - mval) + __expf(v3.w - mval);
        #pragma unroll
        for (int off = 32; off > 0; off >>= 1) s += __shfl_xor(s, off, 64);

        // target logit: uniform (jt, et) select chain — no runtime array index
        const int t   = targets[row];
        const int c4t = t >> 2;
        const int lt  = c4t & 63;
        const int jt  = c4t >> 6;
        const int et  = t & 3;
        f32x4 vv = (jt == 0) ? v0 : (jt == 1) ? v1 : (jt == 2) ? v2 : v3;
        float  xe = (et == 0) ? vv.x : (et == 1) ? vv.y : (et == 2) ? vv.z : vv.w;
        float tval = __shfl(xe, lt, 64);

        if (lane == 0) {
            float pen = penalty[(size_t)t * NCLASS + midx];
            acc += (mval + __logf(s) - tval) * pen;
        }
    }

    __shared__ float wsum[WPB];
    if (lane == 0) wsum[widx] = acc;
    __syncthreads();
    if (threadIdx.x == 0)
        partials[blockIdx.x] = wsum[0] + wsum[1] + wsum[2] + wsum[3];
}

__global__ __launch_bounds__(1024) void cal_final(
    const float* __restrict__ partials, int n, float* __restrict__ out, float invB)
{
    const int lane = threadIdx.x & 63;
    const int widx = threadIdx.x >> 6;
    float s = 0.0f;
    for (int i = threadIdx.x; i < n; i += 1024) s += partials[i];
    #pragma unroll
    for (int off = 32; off > 0; off >>= 1) s += __shfl_xor(s, off, 64);
    __shared__ float wsum[16];
    if (lane == 0) wsum[widx] = s;
    __syncthreads();
    if (threadIdx.x == 0) {
        float t = 0.0f;
        #pragma unroll
        for (int i = 0; i < 16; ++i) t += wsum[i];
        out[0] = t * invB;
    }
}

extern "C" void kernel_launch(void* const* d_in, const int* in_sizes, int n_in,
                              void* d_out, int out_size, void* d_ws, size_t ws_size,
                              hipStream_t stream)
{
    const float* outputs = (const float*)d_in[0];
    const int*   targets = (const int*)d_in[1];
    const float* penalty = (const float*)d_in[2];
    float* out = (float*)d_out;
    const int B = in_sizes[1];

    int grid = NBLOCKS;
    float* partials = (float*)d_ws;
    if (ws_size < (size_t)grid * sizeof(float))
        grid = (int)(ws_size / sizeof(float));   // defensive; expect ws >= 8 KB

    cal_rows<<<grid, BLK, 0, stream>>>(outputs, targets, penalty, partials, B);
    cal_final<<<1, 1024, 0, stream>>>(partials, grid, out, 1.0f / (float)B);
}